// Round 6
// baseline (599.161 us; speedup 1.0000x reference)
//
#include <hip/hip_runtime.h>

// Shapes fixed by the reference setup.
#define BB 32
#define HH 16
#define NN 1024
#define DD 128

// K1: one block per (b,h) row, 1024 threads = 16 waves = 32 half-waves.
//   Phase A: padd[b] = first index with padding==0 (else N), block-min reduce.
//   Phase B: score[n] = dot(t[bh,n,:], w2)  (half-wave per 32-row group,
//            4-deep load pipeline + pair-merged butterfly reduce).
//   Phase C: masked softmax -> factor[n] = 1 + attn[n] written to global ws.
//   Pure-read bound: 512 KB of t per block, 2 KB factor out.
__global__ __launch_bounds__(1024) void score_softmax_kernel(const float* __restrict__ t,
                                                             const int* __restrict__ padding,
                                                             const float* __restrict__ w2,
                                                             float* __restrict__ fac) {
    const int bh   = blockIdx.x;        // 0..B*H-1
    const int b    = bh >> 4;           // H = 16
    const int tid  = threadIdx.x;       // 0..1023
    const int wid  = tid >> 6;          // wave 0..15
    const int lane = tid & 63;

    __shared__ float s_fac[NN];
    __shared__ int   red_i[16];
    __shared__ float red_f[16];

    const float* trow = t + (long)bh * NN * DD;

    // ---- Phase A ----
    int lm = (padding[b * NN + tid] == 0) ? tid : NN;
#pragma unroll
    for (int off = 32; off; off >>= 1) lm = min(lm, __shfl_xor(lm, off));
    if (lane == 0) red_i[wid] = lm;

    // ---- Phase B ----
    const int hw = tid >> 5;            // 0..31
    const int l  = tid & 31;
    const float4 wv = ((const float4*)w2)[l];
    const float4* rowp = (const float4*)(trow + (long)(hw * 32) * DD);

    float4 cur[4], nxt[4];
#pragma unroll
    for (int j = 0; j < 4; ++j) cur[j] = rowp[j * 32 + l];

#pragma unroll
    for (int g = 0; g < 8; ++g) {
        if (g < 7) {
#pragma unroll
            for (int j = 0; j < 4; ++j) nxt[j] = rowp[(g + 1) * 128 + j * 32 + l];
        }
        float p[4];
#pragma unroll
        for (int j = 0; j < 4; ++j)
            p[j] = cur[j].x * wv.x + cur[j].y * wv.y + cur[j].z * wv.z + cur[j].w * wv.w;

#pragma unroll
        for (int pr = 0; pr < 2; ++pr) {
            const float a = p[2 * pr], bq = p[2 * pr + 1];
            float x = (l < 16) ? a : bq;
            float y = (l < 16) ? bq : a;
            x += __shfl_xor(y, 16);
            x += __shfl_xor(x, 8);
            x += __shfl_xor(x, 4);
            x += __shfl_xor(x, 2);
            x += __shfl_xor(x, 1);
            const int n = hw * 32 + g * 4 + 2 * pr;
            if (l == 0)  s_fac[n]     = x;
            if (l == 16) s_fac[n + 1] = x;
        }
        if (g < 7) {
#pragma unroll
            for (int j = 0; j < 4; ++j) cur[j] = nxt[j];
        }
    }
    __syncthreads();

    int padd = NN;
#pragma unroll
    for (int k = 0; k < 16; ++k) padd = min(padd, red_i[k]);

    // ---- Phase C ----
    const float sc  = s_fac[tid];
    const float NEG = -3.4e38f;
    float m = (tid < padd) ? sc : NEG;
#pragma unroll
    for (int off = 32; off; off >>= 1) m = fmaxf(m, __shfl_xor(m, off));
    if (lane == 0) red_f[wid] = m;
    __syncthreads();
    float M = NEG;
#pragma unroll
    for (int k = 0; k < 16; ++k) M = fmaxf(M, red_f[k]);
    __syncthreads();

    const float e = (tid < padd) ? __expf(sc - M) : 0.f;
    float s = e;
#pragma unroll
    for (int off = 32; off; off >>= 1) s += __shfl_xor(s, off);
    if (lane == 0) red_f[wid] = s;
    __syncthreads();
    float S = 0.f;
#pragma unroll
    for (int k = 0; k < 16; ++k) S += red_f[k];

    const float inv = (S > 0.f) ? (1.0f / S) : 0.f;
    fac[(long)bh * NN + tid] = 1.f + e * inv;   // masked n -> exactly 1
}

// K2: out = t * factor[row]. Pure streaming copy-scale; t re-read should hit
// the L3 that K1 just populated. No barriers, no LDS, fill-like structure.
__global__ __launch_bounds__(256) void mul_kernel(const float* __restrict__ t,
                                                  const float* __restrict__ fac,
                                                  float* __restrict__ out) {
    const long total4 = (long)BB * HH * NN * DD / 4;      // 16777216 float4
    const long stride = (long)gridDim.x * 256;
    for (long i = (long)blockIdx.x * 256 + threadIdx.x; i < total4; i += stride) {
        const float f = fac[i >> 5];                      // 32 float4 per D=128 row
        float4 v = ((const float4*)t)[i];
        v.x *= f; v.y *= f; v.z *= f; v.w *= f;
        ((float4*)out)[i] = v;
    }
}

extern "C" void kernel_launch(void* const* d_in, const int* in_sizes, int n_in,
                              void* d_out, int out_size, void* d_ws, size_t ws_size,
                              hipStream_t stream) {
    // inputs: 0 t_1 (unused — softmax shift-invariance), 1 t, 2 padding, 3 N,
    //         4 concat_w (w1 unused | w2), 5 concat_b (unused — cancels)
    const float* t       = (const float*)d_in[1];
    const int*   padding = (const int*)d_in[2];
    const float* cw      = (const float*)d_in[4];
    float*       out     = (float*)d_out;
    float*       fac     = (float*)d_ws;   // B*H*N floats = 2 MB

    score_softmax_kernel<<<BB * HH, 1024, 0, stream>>>(t, padding, cw + DD, fac);
    mul_kernel<<<8192, 256, 0, stream>>>(t, fac, out);
}